// Round 1
// baseline (2454.882 us; speedup 1.0000x reference)
//
#include <hip/hip_runtime.h>

#define N_NODES 10000
#define N_EDGES 50000
#define IN0     32
#define EDGE_IN 16
#define GIN     8
#define HID     64
#define NG      64
#define KDIM    128
#define EPS     1e-5f

// ---------------------------------------------------------------------------
// h = relu(edge_attr @ w1 + b1)   [E,16]@[16,128] -> [E,128]
__global__ __launch_bounds__(256) void h_kernel(const float* __restrict__ ea,
                                                const float* __restrict__ w1,
                                                const float* __restrict__ b1,
                                                float* __restrict__ h) {
    size_t idx = (size_t)blockIdx.x * 256 + threadIdx.x;
    if (idx >= (size_t)N_EDGES * KDIM) return;
    int j = (int)(idx & 127);
    size_t e = idx >> 7;
    const float* ear = ea + e * EDGE_IN;
    float acc = b1[j];
#pragma unroll
    for (int t = 0; t < EDGE_IN; t++) acc += ear[t] * w1[t * KDIM + j];
    h[idx] = fmaxf(acc, 0.f);
}

// ---------------------------------------------------------------------------
// xb2[n,o] = sum_i x[n,i] * b2[i*64+o]   (the enn b2 contribution per node)
__global__ __launch_bounds__(256) void xb2_kernel(const float* __restrict__ x,
                                                  const float* __restrict__ b2,
                                                  float* __restrict__ xb2,
                                                  int in, int inshift) {
    __shared__ float xs[4][64];
    const int o = threadIdx.x & 63, nl = threadIdx.x >> 6;
    const int n0 = blockIdx.x * 4;
    for (int idx = threadIdx.x; idx < (4 << inshift); idx += 256) {
        int r = idx >> inshift, i = idx & (in - 1);
        xs[r][i] = (n0 + r < N_NODES) ? x[(size_t)(n0 + r) * in + i] : 0.f;
    }
    __syncthreads();
    int n = n0 + nl;
    if (n >= N_NODES) return;
    float acc = 0.f;
#pragma unroll 8
    for (int i = 0; i < in; i++) acc += xs[nl][i] * b2[i * 64 + o];
    xb2[(size_t)n * 64 + o] = acc;
}

// ---------------------------------------------------------------------------
// Y[v, kk, o] = sum_i x[v,i] * w2[kbase+kk, i*64+o]
// One block: 64 nodes x 64 o for one kk. C tile 64x64, K = in (32 or 64).
__global__ __launch_bounds__(256) void ygemm(const float* __restrict__ x,
                                             const float* __restrict__ w2,
                                             float* __restrict__ Y,
                                             int in, int inshift, int rowlen,
                                             int kbase, int kchunk) {
    __shared__ float As[64][68];  // transposed: As[i][r] = x[v0+r, i]
    __shared__ float Bs[64][68];  // Bs[i][o]   = w2[k, i*64+o]
    const int kk = blockIdx.y;
    const int v0 = blockIdx.x * 64;
    const float* Bp = w2 + (size_t)(kbase + kk) * rowlen;
    for (int idx = threadIdx.x; idx < (in << 6); idx += 256)
        Bs[idx >> 6][idx & 63] = Bp[idx];
    for (int idx = threadIdx.x; idx < (in << 6); idx += 256) {
        int r = idx >> inshift, i = idx & (in - 1);
        As[i][r] = (v0 + r < N_NODES) ? x[(size_t)(v0 + r) * in + i] : 0.f;
    }
    __syncthreads();
    const int tx = threadIdx.x & 15, ty = threadIdx.x >> 4;
    const int o0 = tx * 4, r0 = ty * 4;
    float acc[4][4] = {};
#pragma unroll 8
    for (int i = 0; i < in; i++) {
        float4 av = *reinterpret_cast<const float4*>(&As[i][r0]);
        float4 bv = *reinterpret_cast<const float4*>(&Bs[i][o0]);
        const float a[4] = {av.x, av.y, av.z, av.w};
        const float b[4] = {bv.x, bv.y, bv.z, bv.w};
#pragma unroll
        for (int r = 0; r < 4; r++)
#pragma unroll
            for (int c = 0; c < 4; c++) acc[r][c] += a[r] * b[c];
    }
#pragma unroll
    for (int r = 0; r < 4; r++) {
        int v = v0 + r0 + r;
        if (v < N_NODES) {
            float4 val;
            val.x = acc[r][0]; val.y = acc[r][1]; val.z = acc[r][2]; val.w = acc[r][3];
            *reinterpret_cast<float4*>(&Y[((size_t)v * kchunk + kk) * 64 + o0]) = val;
        }
    }
}

// ---------------------------------------------------------------------------
// msg[e,o] (+)= sum_k h[e,kbase+k] * Y[src[e],k,o]; first chunk seeds with xb2,
// last chunk scatters to agg[dst] with atomics.
__global__ __launch_bounds__(256) void msg_kernel(const float* __restrict__ h,
                                                  const float* __restrict__ Y,
                                                  const int* __restrict__ src,
                                                  const int* __restrict__ dst,
                                                  float* __restrict__ msg,
                                                  const float* __restrict__ xb2,
                                                  float* __restrict__ agg,
                                                  int kbase, int kchunk,
                                                  int first, int last) {
    int p = blockIdx.x * 4 + (threadIdx.x >> 6);
    if (p >= N_EDGES) return;
    const int o = threadIdx.x & 63;
    const int s = src[p];
    const float* yrow = Y + (size_t)s * ((size_t)kchunk << 6) + o;
    float hreg = (o < kchunk) ? h[(size_t)p * KDIM + kbase + o] : 0.f;
    float acc = first ? xb2[(size_t)s * 64 + o] : msg[(size_t)p * 64 + o];
#pragma unroll 8
    for (int k = 0; k < kchunk; k++)
        acc += __shfl(hreg, k, 64) * yrow[(size_t)k << 6];
    if (last) atomicAdd(&agg[(size_t)dst[p] * 64 + o], acc);
    else      msg[(size_t)p * 64 + o] = acc;
}

// ---------------------------------------------------------------------------
// pre[n,o] = agg[n,o] + sum_i x[n,i]*root[i,o] + bias[o]; accumulate BN stats.
__global__ __launch_bounds__(256) void pre_stats(const float* __restrict__ agg,
                                                 const float* __restrict__ x,
                                                 const float* __restrict__ root,
                                                 const float* __restrict__ bias,
                                                 float* __restrict__ pre,
                                                 float* __restrict__ stats,
                                                 int in, int inshift) {
    __shared__ float xs[4][64];
    __shared__ float lsum[64], lsq[64];
    const int o = threadIdx.x & 63, nl = threadIdx.x >> 6;
    if (threadIdx.x < 64) { lsum[threadIdx.x] = 0.f; lsq[threadIdx.x] = 0.f; }
    const float bo = bias[o];
    for (int n0 = blockIdx.x * 4; n0 < N_NODES; n0 += gridDim.x * 4) {
        __syncthreads();
        for (int idx = threadIdx.x; idx < (4 << inshift); idx += 256) {
            int r = idx >> inshift, i = idx & (in - 1);
            if (n0 + r < N_NODES) xs[r][i] = x[(size_t)(n0 + r) * in + i];
        }
        __syncthreads();
        int n = n0 + nl;
        if (n < N_NODES) {
            float acc = agg[(size_t)n * 64 + o] + bo;
#pragma unroll 8
            for (int i = 0; i < in; i++) acc += xs[nl][i] * root[i * 64 + o];
            pre[(size_t)n * 64 + o] = acc;
            atomicAdd(&lsum[o], acc);
            atomicAdd(&lsq[o], acc * acc);
        }
    }
    __syncthreads();
    if (threadIdx.x < 64) {
        atomicAdd(&stats[threadIdx.x], lsum[threadIdx.x]);
        atomicAdd(&stats[64 + threadIdx.x], lsq[threadIdx.x]);
    }
}

// ---------------------------------------------------------------------------
// BN (batch stats, biased var) + ReLU. mode 0: store xn. mode 1: segment-max pool.
__global__ __launch_bounds__(256) void bn_apply(const float* __restrict__ pre,
                                                const float* __restrict__ stats,
                                                const float* __restrict__ gamma,
                                                const float* __restrict__ beta,
                                                float* __restrict__ xn,
                                                const int* __restrict__ batch,
                                                float* __restrict__ pooled,
                                                int mode) {
    int idx = blockIdx.x * 256 + threadIdx.x;
    if (idx >= N_NODES * 64) return;
    const int o = idx & 63, n = idx >> 6;
    const float inv = 1.f / (float)N_NODES;
    float mu = stats[o] * inv;
    float var = stats[64 + o] * inv - mu * mu;
    float sc = gamma[o] * rsqrtf(var + EPS);
    float sh = beta[o] - mu * sc;
    float v = fmaxf(pre[idx] * sc + sh, 0.f);
    if (mode == 0) xn[idx] = v;
    else atomicMax((int*)&pooled[(size_t)batch[n] * 64 + o], __float_as_int(v));
}

// ---------------------------------------------------------------------------
// out[g] = pp_b2 + relu(cat(pooled[g],u[g]) @ pp_w1 + pp_b1) @ pp_w2
__global__ __launch_bounds__(64) void final_mlp(const float* __restrict__ pooled,
                                                const float* __restrict__ u,
                                                const float* __restrict__ w1,
                                                const float* __restrict__ b1,
                                                const float* __restrict__ w2,
                                                const float* __restrict__ b2,
                                                float* __restrict__ out) {
    const int g = blockIdx.x, t = threadIdx.x;
    float acc = b1[t];
#pragma unroll 8
    for (int i = 0; i < 64; i++) acc += pooled[g * 64 + i] * w1[i * 64 + t];
#pragma unroll
    for (int j = 0; j < GIN; j++) acc += u[g * GIN + j] * w1[(64 + j) * 64 + t];
    float hv = fmaxf(acc, 0.f) * w2[t];
#pragma unroll
    for (int off = 32; off > 0; off >>= 1) hv += __shfl_down(hv, off, 64);
    if (t == 0) out[g] = hv + b2[0];
}

// ---------------------------------------------------------------------------
extern "C" void kernel_launch(void* const* d_in, const int* in_sizes, int n_in,
                              void* d_out, int out_size, void* d_ws, size_t ws_size,
                              hipStream_t stream) {
    const float* x0      = (const float*)d_in[0];
    const int*   ei      = (const int*)d_in[1];
    const int*   src     = ei;
    const int*   dst     = ei + N_EDGES;
    const float* ea      = (const float*)d_in[2];
    const int*   batch   = (const int*)d_in[3];
    const float* u       = (const float*)d_in[4];
    const float* e0w1    = (const float*)d_in[5];
    const float* e0b1    = (const float*)d_in[6];
    const float* e0w2    = (const float*)d_in[7];
    const float* e0b2    = (const float*)d_in[8];
    const float* root0   = (const float*)d_in[9];
    const float* bias0   = (const float*)d_in[10];
    const float* gamma0  = (const float*)d_in[11];
    const float* beta0   = (const float*)d_in[12];
    const float* ew1     = (const float*)d_in[13];
    const float* eb1     = (const float*)d_in[14];
    const float* ew2     = (const float*)d_in[15];
    const float* eb2     = (const float*)d_in[16];
    const float* rootl   = (const float*)d_in[17];
    const float* biasl   = (const float*)d_in[18];
    const float* gammal  = (const float*)d_in[19];
    const float* betal   = (const float*)d_in[20];
    const float* pp_w1   = (const float*)d_in[21];
    const float* pp_b1   = (const float*)d_in[22];
    const float* pp_w2   = (const float*)d_in[23];
    const float* pp_b2   = (const float*)d_in[24];

    float* ws = (float*)d_ws;
    size_t off = 0;
    float* h      = ws + off; off += (size_t)N_EDGES * KDIM;   // 6.4M
    float* msg    = ws + off; off += (size_t)N_EDGES * 64;     // 3.2M
    float* agg    = ws + off; off += (size_t)N_NODES * 64;
    float* xa     = ws + off; off += (size_t)N_NODES * 64;
    float* xb     = ws + off; off += (size_t)N_NODES * 64;
    float* xb2    = ws + off; off += (size_t)N_NODES * 64;
    float* stats  = ws + off; off += 256;
    float* pooled = ws + off; off += (size_t)NG * 64;
    float* Y      = ws + off;

    // pick k-chunking so Y fits in workspace (deterministic given ws_size)
    int kc = 4;
    while (kc < 128 && (off + (size_t)N_NODES * 8192 / kc) * 4 > ws_size) kc <<= 1;
    const int kchunk = KDIM / kc;

    hipMemsetAsync(pooled, 0, (size_t)NG * 64 * 4, stream);

    struct Layer {
        const float *w1, *b1, *w2, *b2, *root, *bias, *gamma, *beta, *xin;
        float* xout; int in, inshift, mode;
    };
    Layer L[4];
    L[0] = {e0w1, e0b1, e0w2, e0b2, root0, bias0, gamma0, beta0, x0, xa, IN0, 5, 0};
    for (int l = 0; l < 3; l++) {
        const float* xin  = (l == 0) ? xa : ((l == 1) ? xb : xa);
        float*       xout = (l == 0) ? xb : ((l == 1) ? xa : nullptr);
        L[l + 1] = {ew1 + (size_t)l * EDGE_IN * KDIM, eb1 + (size_t)l * KDIM,
                    ew2 + (size_t)l * KDIM * (HID * HID), eb2 + (size_t)l * (HID * HID),
                    rootl + (size_t)l * HID * HID, biasl + (size_t)l * HID,
                    gammal + (size_t)l * HID, betal + (size_t)l * HID,
                    xin, xout, HID, 6, (l == 2) ? 1 : 0};
    }

    const int hblocks  = (int)(((size_t)N_EDGES * KDIM + 255) / 256);
    const int nblocks4 = (N_NODES + 3) / 4;
    const int vblocks  = (N_NODES + 63) / 64;
    const int eblocks  = (N_EDGES + 3) / 4;
    const int ablocks  = (N_NODES * 64 + 255) / 256;

    for (int l = 0; l < 4; l++) {
        const Layer& P = L[l];
        const int rowlen = P.in * 64;
        h_kernel<<<hblocks, 256, 0, stream>>>(ea, P.w1, P.b1, h);
        xb2_kernel<<<nblocks4, 256, 0, stream>>>(P.xin, P.b2, xb2, P.in, P.inshift);
        hipMemsetAsync(agg, 0, (size_t)N_NODES * 64 * 4, stream);
        hipMemsetAsync(stats, 0, 128 * 4, stream);
        for (int c = 0; c < kc; c++) {
            ygemm<<<dim3(vblocks, kchunk), 256, 0, stream>>>(
                P.xin, P.w2, Y, P.in, P.inshift, rowlen, c * kchunk, kchunk);
            msg_kernel<<<eblocks, 256, 0, stream>>>(
                h, Y, src, dst, msg, xb2, agg, c * kchunk, kchunk,
                (c == 0) ? 1 : 0, (c == kc - 1) ? 1 : 0);
        }
        pre_stats<<<512, 256, 0, stream>>>(agg, P.xin, P.root, P.bias, agg, stats,
                                           P.in, P.inshift);
        bn_apply<<<ablocks, 256, 0, stream>>>(agg, stats, P.gamma, P.beta, P.xout,
                                              batch, pooled, P.mode);
    }
    final_mlp<<<NG, 64, 0, stream>>>(pooled, u, pp_w1, pp_b1, pp_w2, pp_b2,
                                     (float*)d_out);
}

// Round 2
// 1681.264 us; speedup vs baseline: 1.4601x; 1.4601x over previous
//
#include <hip/hip_runtime.h>

#define N_NODES 10000
#define N_EDGES 50000
#define IN0     32
#define EDGE_IN 16
#define GIN     8
#define HID     64
#define NG      64
#define KDIM    128
#define EPS     1e-5f

// ---------------------------------------------------------------------------
// h = relu(edge_attr @ w1 + b1)   [E,16]@[16,128] -> [E,128]
__global__ __launch_bounds__(256) void h_kernel(const float* __restrict__ ea,
                                                const float* __restrict__ w1,
                                                const float* __restrict__ b1,
                                                float* __restrict__ h) {
    size_t idx = (size_t)blockIdx.x * 256 + threadIdx.x;
    if (idx >= (size_t)N_EDGES * KDIM) return;
    int j = (int)(idx & 127);
    size_t e = idx >> 7;
    const float* ear = ea + e * EDGE_IN;
    float acc = b1[j];
#pragma unroll
    for (int t = 0; t < EDGE_IN; t++) acc += ear[t] * w1[t * KDIM + j];
    h[idx] = fmaxf(acc, 0.f);
}

// ---------------------------------------------------------------------------
// Edge sorting by src: histogram -> scan -> scatter (cheap, once per call)
__global__ __launch_bounds__(256) void hist_kernel(const int* __restrict__ src,
                                                   int* __restrict__ cnt) {
    int e = blockIdx.x * 256 + threadIdx.x;
    if (e < N_EDGES) atomicAdd(&cnt[src[e]], 1);
}

__global__ __launch_bounds__(1024) void scan_kernel(const int* __restrict__ cnt,
                                                    int* __restrict__ offs) {
    __shared__ int part[1024];
    const int t = threadIdx.x;
    const int base = t * 10;
    int s = 0;
#pragma unroll
    for (int i = 0; i < 10; i++) {
        int idx = base + i;
        if (idx < N_NODES) s += cnt[idx];
    }
    part[t] = s;
    __syncthreads();
    for (int d = 1; d < 1024; d <<= 1) {
        int v = (t >= d) ? part[t - d] : 0;
        __syncthreads();
        part[t] += v;
        __syncthreads();
    }
    int run = t ? part[t - 1] : 0;
#pragma unroll
    for (int i = 0; i < 10; i++) {
        int idx = base + i;
        if (idx < N_NODES) { offs[idx] = run; run += cnt[idx]; }
    }
}

__global__ __launch_bounds__(256) void scatter_kernel(const int* __restrict__ src,
                                                      const int* __restrict__ dst,
                                                      const int* __restrict__ offs,
                                                      int* __restrict__ cur,
                                                      int* __restrict__ srcs,
                                                      int* __restrict__ dsts,
                                                      int* __restrict__ perm) {
    int e = blockIdx.x * 256 + threadIdx.x;
    if (e >= N_EDGES) return;
    int s = src[e];
    int pos = offs[s] + atomicAdd(&cur[s], 1);
    srcs[pos] = s;
    dsts[pos] = dst[e];
    perm[pos] = e;
}

// ---------------------------------------------------------------------------
// xb2[n,o] = sum_i x[n,i] * b2[i*64+o]   (the enn b2 contribution per node)
__global__ __launch_bounds__(256) void xb2_kernel(const float* __restrict__ x,
                                                  const float* __restrict__ b2,
                                                  float* __restrict__ xb2,
                                                  int in, int inshift) {
    __shared__ float xs[4][64];
    const int o = threadIdx.x & 63, nl = threadIdx.x >> 6;
    const int n0 = blockIdx.x * 4;
    for (int idx = threadIdx.x; idx < (4 << inshift); idx += 256) {
        int r = idx >> inshift, i = idx & (in - 1);
        xs[r][i] = (n0 + r < N_NODES) ? x[(size_t)(n0 + r) * in + i] : 0.f;
    }
    __syncthreads();
    int n = n0 + nl;
    if (n >= N_NODES) return;
    float acc = 0.f;
#pragma unroll 8
    for (int i = 0; i < in; i++) acc += xs[nl][i] * b2[i * 64 + o];
    xb2[(size_t)n * 64 + o] = acc;
}

// ---------------------------------------------------------------------------
// Y[v, kk, o] = sum_i x[v,i] * w2[kbase+kk, i*64+o]
__global__ __launch_bounds__(256) void ygemm(const float* __restrict__ x,
                                             const float* __restrict__ w2,
                                             float* __restrict__ Y,
                                             int in, int inshift, int rowlen,
                                             int kbase, int kchunk) {
    __shared__ float As[64][68];  // transposed: As[i][r] = x[v0+r, i]
    __shared__ float Bs[64][68];  // Bs[i][o]   = w2[k, i*64+o]
    const int kk = blockIdx.y;
    const int v0 = blockIdx.x * 64;
    const float* Bp = w2 + (size_t)(kbase + kk) * rowlen;
    for (int idx = threadIdx.x; idx < (in << 6); idx += 256)
        Bs[idx >> 6][idx & 63] = Bp[idx];
    for (int idx = threadIdx.x; idx < (in << 6); idx += 256) {
        int r = idx >> inshift, i = idx & (in - 1);
        As[i][r] = (v0 + r < N_NODES) ? x[(size_t)(v0 + r) * in + i] : 0.f;
    }
    __syncthreads();
    const int tx = threadIdx.x & 15, ty = threadIdx.x >> 4;
    const int o0 = tx * 4, r0 = ty * 4;
    float acc[4][4] = {};
#pragma unroll 8
    for (int i = 0; i < in; i++) {
        float4 av = *reinterpret_cast<const float4*>(&As[i][r0]);
        float4 bv = *reinterpret_cast<const float4*>(&Bs[i][o0]);
        const float a[4] = {av.x, av.y, av.z, av.w};
        const float b[4] = {bv.x, bv.y, bv.z, bv.w};
#pragma unroll
        for (int r = 0; r < 4; r++)
#pragma unroll
            for (int c = 0; c < 4; c++) acc[r][c] += a[r] * b[c];
    }
#pragma unroll
    for (int r = 0; r < 4; r++) {
        int v = v0 + r0 + r;
        if (v < N_NODES) {
            float4 val;
            val.x = acc[r][0]; val.y = acc[r][1]; val.z = acc[r][2]; val.w = acc[r][3];
            *reinterpret_cast<float4*>(&Y[((size_t)v * kchunk + kk) * 64 + o0]) = val;
        }
    }
}

// ---------------------------------------------------------------------------
// msg over sorted edges. One wave = one edge; 16 lanes x float4 over o,
// 4-way k-parallel, shfl_xor reduction. 16 edges/block for L1/L2 reuse of
// Y rows (edges sorted by src).
__global__ __launch_bounds__(1024) void msg_kernel(const float* __restrict__ h,
                                                   const float* __restrict__ Y,
                                                   const int* __restrict__ srcs,
                                                   const int* __restrict__ dsts,
                                                   const int* __restrict__ perm,
                                                   float* __restrict__ msg,
                                                   const float* __restrict__ xb2,
                                                   float* __restrict__ agg,
                                                   int kbase, int kchunk,
                                                   int first, int last) {
    int p = blockIdx.x * 16 + (threadIdx.x >> 6);
    if (p >= N_EDGES) return;
    const int lane = threadIdx.x & 63;
    const int og = lane & 15, kg = lane >> 4;
    const int s = srcs[p];
    const int eo = perm[p];
    float hreg = (lane < kchunk) ? h[(size_t)eo * KDIM + kbase + lane] : 0.f;
    const float* yrow = Y + (size_t)s * ((size_t)kchunk << 6) + og * 4;
    float4 acc = {0.f, 0.f, 0.f, 0.f};
#pragma unroll 8
    for (int k = kg; k < kchunk; k += 4) {
        float hv = __shfl(hreg, k, 64);
        float4 yv = *reinterpret_cast<const float4*>(yrow + ((size_t)k << 6));
        acc.x += hv * yv.x; acc.y += hv * yv.y;
        acc.z += hv * yv.z; acc.w += hv * yv.w;
    }
#pragma unroll
    for (int m = 16; m <= 32; m <<= 1) {
        acc.x += __shfl_xor(acc.x, m, 64);
        acc.y += __shfl_xor(acc.y, m, 64);
        acc.z += __shfl_xor(acc.z, m, 64);
        acc.w += __shfl_xor(acc.w, m, 64);
    }
    if (last) {
        int o = og * 4 + kg;
        float v = (kg == 0) ? acc.x : (kg == 1) ? acc.y : (kg == 2) ? acc.z : acc.w;
        float base = first ? xb2[(size_t)s * 64 + o] : msg[(size_t)p * 64 + o];
        atomicAdd(&agg[(size_t)dsts[p] * 64 + o], v + base);
    } else if (kg == 0) {
        float4 base = first ? *reinterpret_cast<const float4*>(&xb2[(size_t)s * 64 + og * 4])
                            : *reinterpret_cast<const float4*>(&msg[(size_t)p * 64 + og * 4]);
        acc.x += base.x; acc.y += base.y; acc.z += base.z; acc.w += base.w;
        *reinterpret_cast<float4*>(&msg[(size_t)p * 64 + og * 4]) = acc;
    }
}

// ---------------------------------------------------------------------------
// pre[n,o] = agg[n,o] + sum_i x[n,i]*root[i,o] + bias[o]; accumulate BN stats.
__global__ __launch_bounds__(256) void pre_stats(const float* __restrict__ agg,
                                                 const float* __restrict__ x,
                                                 const float* __restrict__ root,
                                                 const float* __restrict__ bias,
                                                 float* __restrict__ pre,
                                                 float* __restrict__ stats,
                                                 int in, int inshift) {
    __shared__ float xs[4][64];
    __shared__ float lsum[64], lsq[64];
    const int o = threadIdx.x & 63, nl = threadIdx.x >> 6;
    if (threadIdx.x < 64) { lsum[threadIdx.x] = 0.f; lsq[threadIdx.x] = 0.f; }
    const float bo = bias[o];
    for (int n0 = blockIdx.x * 4; n0 < N_NODES; n0 += gridDim.x * 4) {
        __syncthreads();
        for (int idx = threadIdx.x; idx < (4 << inshift); idx += 256) {
            int r = idx >> inshift, i = idx & (in - 1);
            if (n0 + r < N_NODES) xs[r][i] = x[(size_t)(n0 + r) * in + i];
        }
        __syncthreads();
        int n = n0 + nl;
        if (n < N_NODES) {
            float acc = agg[(size_t)n * 64 + o] + bo;
#pragma unroll 8
            for (int i = 0; i < in; i++) acc += xs[nl][i] * root[i * 64 + o];
            pre[(size_t)n * 64 + o] = acc;
            atomicAdd(&lsum[o], acc);
            atomicAdd(&lsq[o], acc * acc);
        }
    }
    __syncthreads();
    if (threadIdx.x < 64) {
        atomicAdd(&stats[threadIdx.x], lsum[threadIdx.x]);
        atomicAdd(&stats[64 + threadIdx.x], lsq[threadIdx.x]);
    }
}

// ---------------------------------------------------------------------------
// BN (batch stats, biased var) + ReLU. mode 0: store xn. mode 1: segment-max pool.
__global__ __launch_bounds__(256) void bn_apply(const float* __restrict__ pre,
                                                const float* __restrict__ stats,
                                                const float* __restrict__ gamma,
                                                const float* __restrict__ beta,
                                                float* __restrict__ xn,
                                                const int* __restrict__ batch,
                                                float* __restrict__ pooled,
                                                int mode) {
    int idx = blockIdx.x * 256 + threadIdx.x;
    if (idx >= N_NODES * 64) return;
    const int o = idx & 63, n = idx >> 6;
    const float inv = 1.f / (float)N_NODES;
    float mu = stats[o] * inv;
    float var = stats[64 + o] * inv - mu * mu;
    float sc = gamma[o] * rsqrtf(var + EPS);
    float sh = beta[o] - mu * sc;
    float v = fmaxf(pre[idx] * sc + sh, 0.f);
    if (mode == 0) xn[idx] = v;
    else atomicMax((int*)&pooled[(size_t)batch[n] * 64 + o], __float_as_int(v));
}

// ---------------------------------------------------------------------------
// out[g] = pp_b2 + relu(cat(pooled[g],u[g]) @ pp_w1 + pp_b1) @ pp_w2
__global__ __launch_bounds__(64) void final_mlp(const float* __restrict__ pooled,
                                                const float* __restrict__ u,
                                                const float* __restrict__ w1,
                                                const float* __restrict__ b1,
                                                const float* __restrict__ w2,
                                                const float* __restrict__ b2,
                                                float* __restrict__ out) {
    const int g = blockIdx.x, t = threadIdx.x;
    float acc = b1[t];
#pragma unroll 8
    for (int i = 0; i < 64; i++) acc += pooled[g * 64 + i] * w1[i * 64 + t];
#pragma unroll
    for (int j = 0; j < GIN; j++) acc += u[g * GIN + j] * w1[(64 + j) * 64 + t];
    float hv = fmaxf(acc, 0.f) * w2[t];
#pragma unroll
    for (int off = 32; off > 0; off >>= 1) hv += __shfl_down(hv, off, 64);
    if (t == 0) out[g] = hv + b2[0];
}

// ---------------------------------------------------------------------------
extern "C" void kernel_launch(void* const* d_in, const int* in_sizes, int n_in,
                              void* d_out, int out_size, void* d_ws, size_t ws_size,
                              hipStream_t stream) {
    const float* x0      = (const float*)d_in[0];
    const int*   ei      = (const int*)d_in[1];
    const int*   src     = ei;
    const int*   dst     = ei + N_EDGES;
    const float* ea      = (const float*)d_in[2];
    const int*   batch   = (const int*)d_in[3];
    const float* u       = (const float*)d_in[4];
    const float* e0w1    = (const float*)d_in[5];
    const float* e0b1    = (const float*)d_in[6];
    const float* e0w2    = (const float*)d_in[7];
    const float* e0b2    = (const float*)d_in[8];
    const float* root0   = (const float*)d_in[9];
    const float* bias0   = (const float*)d_in[10];
    const float* gamma0  = (const float*)d_in[11];
    const float* beta0   = (const float*)d_in[12];
    const float* ew1     = (const float*)d_in[13];
    const float* eb1     = (const float*)d_in[14];
    const float* ew2     = (const float*)d_in[15];
    const float* eb2     = (const float*)d_in[16];
    const float* rootl   = (const float*)d_in[17];
    const float* biasl   = (const float*)d_in[18];
    const float* gammal  = (const float*)d_in[19];
    const float* betal   = (const float*)d_in[20];
    const float* pp_w1   = (const float*)d_in[21];
    const float* pp_b1   = (const float*)d_in[22];
    const float* pp_w2   = (const float*)d_in[23];
    const float* pp_b2   = (const float*)d_in[24];

    float* ws = (float*)d_ws;
    size_t off = 0;
    float* h      = ws + off; off += (size_t)N_EDGES * KDIM;   // 6.4M
    float* msg    = ws + off; off += (size_t)N_EDGES * 64;     // 3.2M
    float* agg    = ws + off; off += (size_t)N_NODES * 64;
    float* xa     = ws + off; off += (size_t)N_NODES * 64;
    float* xb     = ws + off; off += (size_t)N_NODES * 64;
    float* xb2    = ws + off; off += (size_t)N_NODES * 64;
    float* stats  = ws + off; off += 256;
    float* pooled = ws + off; off += (size_t)NG * 64;
    int*   cnt    = (int*)(ws + off); off += N_NODES;
    int*   offs   = (int*)(ws + off); off += N_NODES;
    int*   cur    = (int*)(ws + off); off += N_NODES;
    int*   srcs   = (int*)(ws + off); off += N_EDGES;
    int*   dsts   = (int*)(ws + off); off += N_EDGES;
    int*   perm   = (int*)(ws + off); off += N_EDGES;
    float* Y      = ws + off;

    // pick k-chunking so Y fits in workspace (deterministic given ws_size)
    int kc = 4;
    while (kc < 128 && (off + (size_t)N_NODES * 8192 / kc) * 4 > ws_size) kc <<= 1;
    const int kchunk = KDIM / kc;

    hipMemsetAsync(pooled, 0, (size_t)NG * 64 * 4, stream);
    hipMemsetAsync(cnt, 0, N_NODES * 4, stream);
    hipMemsetAsync(cur, 0, N_NODES * 4, stream);

    const int e256 = (N_EDGES + 255) / 256;
    hist_kernel<<<e256, 256, 0, stream>>>(src, cnt);
    scan_kernel<<<1, 1024, 0, stream>>>(cnt, offs);
    scatter_kernel<<<e256, 256, 0, stream>>>(src, dst, offs, cur, srcs, dsts, perm);

    struct Layer {
        const float *w1, *b1, *w2, *b2, *root, *bias, *gamma, *beta, *xin;
        float* xout; int in, inshift, mode;
    };
    Layer L[4];
    L[0] = {e0w1, e0b1, e0w2, e0b2, root0, bias0, gamma0, beta0, x0, xa, IN0, 5, 0};
    for (int l = 0; l < 3; l++) {
        const float* xin  = (l == 0) ? xa : ((l == 1) ? xb : xa);
        float*       xout = (l == 0) ? xb : ((l == 1) ? xa : nullptr);
        L[l + 1] = {ew1 + (size_t)l * EDGE_IN * KDIM, eb1 + (size_t)l * KDIM,
                    ew2 + (size_t)l * KDIM * (HID * HID), eb2 + (size_t)l * (HID * HID),
                    rootl + (size_t)l * HID * HID, biasl + (size_t)l * HID,
                    gammal + (size_t)l * HID, betal + (size_t)l * HID,
                    xin, xout, HID, 6, (l == 2) ? 1 : 0};
    }

    const int hblocks  = (int)(((size_t)N_EDGES * KDIM + 255) / 256);
    const int nblocks4 = (N_NODES + 3) / 4;
    const int vblocks  = (N_NODES + 63) / 64;
    const int eblocks  = (N_EDGES + 15) / 16;
    const int ablocks  = (N_NODES * 64 + 255) / 256;

    for (int l = 0; l < 4; l++) {
        const Layer& P = L[l];
        const int rowlen = P.in * 64;
        h_kernel<<<hblocks, 256, 0, stream>>>(ea, P.w1, P.b1, h);
        xb2_kernel<<<nblocks4, 256, 0, stream>>>(P.xin, P.b2, xb2, P.in, P.inshift);
        hipMemsetAsync(agg, 0, (size_t)N_NODES * 64 * 4, stream);
        hipMemsetAsync(stats, 0, 128 * 4, stream);
        for (int c = 0; c < kc; c++) {
            ygemm<<<dim3(vblocks, kchunk), 256, 0, stream>>>(
                P.xin, P.w2, Y, P.in, P.inshift, rowlen, c * kchunk, kchunk);
            msg_kernel<<<eblocks, 1024, 0, stream>>>(
                h, Y, srcs, dsts, perm, msg, xb2, agg, c * kchunk, kchunk,
                (c == 0) ? 1 : 0, (c == kc - 1) ? 1 : 0);
        }
        pre_stats<<<512, 256, 0, stream>>>(agg, P.xin, P.root, P.bias, agg, stats,
                                           P.in, P.inshift);
        bn_apply<<<ablocks, 256, 0, stream>>>(agg, stats, P.gamma, P.beta, P.xout,
                                              batch, pooled, P.mode);
    }
    final_mlp<<<NG, 64, 0, stream>>>(pooled, u, pp_w1, pp_b1, pp_w2, pp_b2,
                                     (float*)d_out);
}

// Round 3
// 1360.554 us; speedup vs baseline: 1.8043x; 1.2357x over previous
//
#include <hip/hip_runtime.h>
#include <hip/hip_bf16.h>

#define N_NODES 10000
#define N_EDGES 50000
#define IN0     32
#define EDGE_IN 16
#define GIN     8
#define HID     64
#define NG      64
#define KDIM    128
#define EPS     1e-5f

// ---------------------------------------------------------------------------
// h = relu(edge_attr @ w1 + b1)   [E,16]@[16,128] -> [E,128]
__global__ __launch_bounds__(256) void h_kernel(const float* __restrict__ ea,
                                                const float* __restrict__ w1,
                                                const float* __restrict__ b1,
                                                float* __restrict__ h) {
    size_t idx = (size_t)blockIdx.x * 256 + threadIdx.x;
    if (idx >= (size_t)N_EDGES * KDIM) return;
    int j = (int)(idx & 127);
    size_t e = idx >> 7;
    const float* ear = ea + e * EDGE_IN;
    float acc = b1[j];
#pragma unroll
    for (int t = 0; t < EDGE_IN; t++) acc += ear[t] * w1[t * KDIM + j];
    h[idx] = fmaxf(acc, 0.f);
}

// ---------------------------------------------------------------------------
// Edge sorting by src: histogram -> scan -> scatter (cheap, once per call)
__global__ __launch_bounds__(256) void hist_kernel(const int* __restrict__ src,
                                                   int* __restrict__ cnt) {
    int e = blockIdx.x * 256 + threadIdx.x;
    if (e < N_EDGES) atomicAdd(&cnt[src[e]], 1);
}

__global__ __launch_bounds__(1024) void scan_kernel(const int* __restrict__ cnt,
                                                    int* __restrict__ offs) {
    __shared__ int part[1024];
    const int t = threadIdx.x;
    const int base = t * 10;
    int s = 0;
#pragma unroll
    for (int i = 0; i < 10; i++) {
        int idx = base + i;
        if (idx < N_NODES) s += cnt[idx];
    }
    part[t] = s;
    __syncthreads();
    for (int d = 1; d < 1024; d <<= 1) {
        int v = (t >= d) ? part[t - d] : 0;
        __syncthreads();
        part[t] += v;
        __syncthreads();
    }
    int run = t ? part[t - 1] : 0;
#pragma unroll
    for (int i = 0; i < 10; i++) {
        int idx = base + i;
        if (idx < N_NODES) { offs[idx] = run; run += cnt[idx]; }
    }
}

__global__ __launch_bounds__(256) void scatter_kernel(const int* __restrict__ src,
                                                      const int* __restrict__ dst,
                                                      const int* __restrict__ offs,
                                                      int* __restrict__ cur,
                                                      int* __restrict__ srcs,
                                                      int* __restrict__ dsts,
                                                      int* __restrict__ perm) {
    int e = blockIdx.x * 256 + threadIdx.x;
    if (e >= N_EDGES) return;
    int s = src[e];
    int pos = offs[s] + atomicAdd(&cur[s], 1);
    srcs[pos] = s;
    dsts[pos] = dst[e];
    perm[pos] = e;
}

// ---------------------------------------------------------------------------
// xb2[n,o] = sum_i x[n,i] * b2[i*64+o]
__global__ __launch_bounds__(256) void xb2_kernel(const float* __restrict__ x,
                                                  const float* __restrict__ b2,
                                                  float* __restrict__ xb2,
                                                  int in, int inshift) {
    __shared__ float xs[4][64];
    const int o = threadIdx.x & 63, nl = threadIdx.x >> 6;
    const int n0 = blockIdx.x * 4;
    for (int idx = threadIdx.x; idx < (4 << inshift); idx += 256) {
        int r = idx >> inshift, i = idx & (in - 1);
        xs[r][i] = (n0 + r < N_NODES) ? x[(size_t)(n0 + r) * in + i] : 0.f;
    }
    __syncthreads();
    int n = n0 + nl;
    if (n >= N_NODES) return;
    float acc = 0.f;
#pragma unroll 8
    for (int i = 0; i < in; i++) acc += xs[nl][i] * b2[i * 64 + o];
    xb2[(size_t)n * 64 + o] = acc;
}

// ---------------------------------------------------------------------------
// Y[v, kk, o] = sum_i x[v,i] * w2[kbase+kk, i*64+o]  (fp32 compute, bf16 store)
// Block: 128 nodes x 64 o for one kk. 8x4 acc/thread.
__global__ __launch_bounds__(256) void ygemm(const float* __restrict__ x,
                                             const float* __restrict__ w2,
                                             unsigned short* __restrict__ Y,
                                             int in, int inshift, int rowlen,
                                             int kbase, int kchunk) {
    __shared__ float As[64][132];  // As[i][r] = x[v0+r, i]  (132*4=528B, 16B-aligned rows)
    __shared__ float Bs[64][68];   // Bs[i][o] = w2[k, i*64+o] (68*4=272B, 16B-aligned rows)
    const int kk = blockIdx.y;
    const int v0 = blockIdx.x * 128;
    const float* Bp = w2 + (size_t)(kbase + kk) * rowlen;
    for (int idx = threadIdx.x; idx < (in << 4); idx += 256) {
        float4 bv = reinterpret_cast<const float4*>(Bp)[idx];
        int i = idx >> 4, oq = (idx & 15) << 2;
        *reinterpret_cast<float4*>(&Bs[i][oq]) = bv;
    }
    for (int idx = threadIdx.x; idx < (128 << inshift); idx += 256) {
        int r = idx >> inshift, i = idx & (in - 1);
        As[i][r] = (v0 + r < N_NODES) ? x[(size_t)(v0 + r) * in + i] : 0.f;
    }
    __syncthreads();
    const int tx = threadIdx.x & 15, ty = threadIdx.x >> 4;
    const int o0 = tx * 4, r0 = ty * 8;
    float acc[8][4] = {};
#pragma unroll 4
    for (int i = 0; i < in; i++) {
        float4 a0 = *reinterpret_cast<const float4*>(&As[i][r0]);
        float4 a1 = *reinterpret_cast<const float4*>(&As[i][r0 + 4]);
        float4 bv = *reinterpret_cast<const float4*>(&Bs[i][o0]);
        const float a[8] = {a0.x, a0.y, a0.z, a0.w, a1.x, a1.y, a1.z, a1.w};
        const float b[4] = {bv.x, bv.y, bv.z, bv.w};
#pragma unroll
        for (int r = 0; r < 8; r++)
#pragma unroll
            for (int c = 0; c < 4; c++) acc[r][c] += a[r] * b[c];
    }
#pragma unroll
    for (int r = 0; r < 8; r++) {
        int v = v0 + r0 + r;
        if (v < N_NODES) {
            ushort4 pk;
            __hip_bfloat16 b0 = __float2bfloat16(acc[r][0]);
            __hip_bfloat16 b1 = __float2bfloat16(acc[r][1]);
            __hip_bfloat16 b2 = __float2bfloat16(acc[r][2]);
            __hip_bfloat16 b3 = __float2bfloat16(acc[r][3]);
            pk.x = reinterpret_cast<unsigned short&>(b0);
            pk.y = reinterpret_cast<unsigned short&>(b1);
            pk.z = reinterpret_cast<unsigned short&>(b2);
            pk.w = reinterpret_cast<unsigned short&>(b3);
            *reinterpret_cast<ushort4*>(&Y[((size_t)v * kchunk + kk) * 64 + o0]) = pk;
        }
    }
}

// ---------------------------------------------------------------------------
// msg over sorted edges, bf16 Y. One wave = one edge; 8 o-groups x ushort8
// (16B) loads, 8-way k-parallel, shfl_xor reduce over kg.
__global__ __launch_bounds__(1024) void msg_kernel(const float* __restrict__ h,
                                                   const unsigned short* __restrict__ Y,
                                                   const int* __restrict__ srcs,
                                                   const int* __restrict__ dsts,
                                                   const int* __restrict__ perm,
                                                   float* __restrict__ msg,
                                                   const float* __restrict__ xb2,
                                                   float* __restrict__ agg,
                                                   int kbase, int kchunk,
                                                   int first, int last) {
    int p = blockIdx.x * 16 + (threadIdx.x >> 6);
    if (p >= N_EDGES) return;
    const int lane = threadIdx.x & 63;
    const int og = lane & 7, kg = lane >> 3;
    const int s = srcs[p];
    const int eo = perm[p];
    float hreg = h[(size_t)eo * KDIM + kbase + lane];
    float hreg2 = (kchunk > 64) ? h[(size_t)eo * KDIM + kbase + 64 + lane] : 0.f;
    const unsigned short* yrow = Y + (size_t)s * ((size_t)kchunk << 6) + og * 8;
    float a[8] = {0.f, 0.f, 0.f, 0.f, 0.f, 0.f, 0.f, 0.f};
    for (int k = kg; k < kchunk; k += 8) {
        float hv = __shfl((k & 64) ? hreg2 : hreg, k & 63, 64);
        uint4 yv = *reinterpret_cast<const uint4*>(yrow + ((size_t)k << 6));
        a[0] += hv * __uint_as_float(yv.x << 16);
        a[1] += hv * __uint_as_float(yv.x & 0xffff0000u);
        a[2] += hv * __uint_as_float(yv.y << 16);
        a[3] += hv * __uint_as_float(yv.y & 0xffff0000u);
        a[4] += hv * __uint_as_float(yv.z << 16);
        a[5] += hv * __uint_as_float(yv.z & 0xffff0000u);
        a[6] += hv * __uint_as_float(yv.w << 16);
        a[7] += hv * __uint_as_float(yv.w & 0xffff0000u);
    }
#pragma unroll
    for (int m = 8; m <= 32; m <<= 1)
#pragma unroll
        for (int j = 0; j < 8; j++) a[j] += __shfl_xor(a[j], m, 64);
    const int o = og * 8 + kg;
    float v = a[0];
#pragma unroll
    for (int j = 1; j < 8; j++) v = (kg == j) ? a[j] : v;
    float base = first ? xb2[(size_t)s * 64 + o] : msg[(size_t)p * 64 + o];
    if (last) atomicAdd(&agg[(size_t)dsts[p] * 64 + o], v + base);
    else      msg[(size_t)p * 64 + o] = v + base;
}

// ---------------------------------------------------------------------------
// pre[n,o] = agg[n,o] + sum_i x[n,i]*root[i,o] + bias[o]; accumulate BN stats.
__global__ __launch_bounds__(256) void pre_stats(const float* __restrict__ agg,
                                                 const float* __restrict__ x,
                                                 const float* __restrict__ root,
                                                 const float* __restrict__ bias,
                                                 float* __restrict__ pre,
                                                 float* __restrict__ stats,
                                                 int in, int inshift) {
    __shared__ float xs[4][64];
    __shared__ float lsum[64], lsq[64];
    const int o = threadIdx.x & 63, nl = threadIdx.x >> 6;
    if (threadIdx.x < 64) { lsum[threadIdx.x] = 0.f; lsq[threadIdx.x] = 0.f; }
    const float bo = bias[o];
    for (int n0 = blockIdx.x * 4; n0 < N_NODES; n0 += gridDim.x * 4) {
        __syncthreads();
        for (int idx = threadIdx.x; idx < (4 << inshift); idx += 256) {
            int r = idx >> inshift, i = idx & (in - 1);
            if (n0 + r < N_NODES) xs[r][i] = x[(size_t)(n0 + r) * in + i];
        }
        __syncthreads();
        int n = n0 + nl;
        if (n < N_NODES) {
            float acc = agg[(size_t)n * 64 + o] + bo;
#pragma unroll 8
            for (int i = 0; i < in; i++) acc += xs[nl][i] * root[i * 64 + o];
            pre[(size_t)n * 64 + o] = acc;
            atomicAdd(&lsum[o], acc);
            atomicAdd(&lsq[o], acc * acc);
        }
    }
    __syncthreads();
    if (threadIdx.x < 64) {
        atomicAdd(&stats[threadIdx.x], lsum[threadIdx.x]);
        atomicAdd(&stats[64 + threadIdx.x], lsq[threadIdx.x]);
    }
}

// ---------------------------------------------------------------------------
// BN (batch stats, biased var) + ReLU. mode 0: store xn. mode 1: segment-max pool.
__global__ __launch_bounds__(256) void bn_apply(const float* __restrict__ pre,
                                                const float* __restrict__ stats,
                                                const float* __restrict__ gamma,
                                                const float* __restrict__ beta,
                                                float* __restrict__ xn,
                                                const int* __restrict__ batch,
                                                float* __restrict__ pooled,
                                                int mode) {
    int idx = blockIdx.x * 256 + threadIdx.x;
    if (idx >= N_NODES * 64) return;
    const int o = idx & 63, n = idx >> 6;
    const float inv = 1.f / (float)N_NODES;
    float mu = stats[o] * inv;
    float var = stats[64 + o] * inv - mu * mu;
    float sc = gamma[o] * rsqrtf(var + EPS);
    float sh = beta[o] - mu * sc;
    float v = fmaxf(pre[idx] * sc + sh, 0.f);
    if (mode == 0) xn[idx] = v;
    else atomicMax((int*)&pooled[(size_t)batch[n] * 64 + o], __float_as_int(v));
}

// ---------------------------------------------------------------------------
// out[g] = pp_b2 + relu(cat(pooled[g],u[g]) @ pp_w1 + pp_b1) @ pp_w2
__global__ __launch_bounds__(64) void final_mlp(const float* __restrict__ pooled,
                                                const float* __restrict__ u,
                                                const float* __restrict__ w1,
                                                const float* __restrict__ b1,
                                                const float* __restrict__ w2,
                                                const float* __restrict__ b2,
                                                float* __restrict__ out) {
    const int g = blockIdx.x, t = threadIdx.x;
    float acc = b1[t];
#pragma unroll 8
    for (int i = 0; i < 64; i++) acc += pooled[g * 64 + i] * w1[i * 64 + t];
#pragma unroll
    for (int j = 0; j < GIN; j++) acc += u[g * GIN + j] * w1[(64 + j) * 64 + t];
    float hv = fmaxf(acc, 0.f) * w2[t];
#pragma unroll
    for (int off = 32; off > 0; off >>= 1) hv += __shfl_down(hv, off, 64);
    if (t == 0) out[g] = hv + b2[0];
}

// ---------------------------------------------------------------------------
extern "C" void kernel_launch(void* const* d_in, const int* in_sizes, int n_in,
                              void* d_out, int out_size, void* d_ws, size_t ws_size,
                              hipStream_t stream) {
    const float* x0      = (const float*)d_in[0];
    const int*   ei      = (const int*)d_in[1];
    const int*   src     = ei;
    const int*   dst     = ei + N_EDGES;
    const float* ea      = (const float*)d_in[2];
    const int*   batch   = (const int*)d_in[3];
    const float* u       = (const float*)d_in[4];
    const float* e0w1    = (const float*)d_in[5];
    const float* e0b1    = (const float*)d_in[6];
    const float* e0w2    = (const float*)d_in[7];
    const float* e0b2    = (const float*)d_in[8];
    const float* root0   = (const float*)d_in[9];
    const float* bias0   = (const float*)d_in[10];
    const float* gamma0  = (const float*)d_in[11];
    const float* beta0   = (const float*)d_in[12];
    const float* ew1     = (const float*)d_in[13];
    const float* eb1     = (const float*)d_in[14];
    const float* ew2     = (const float*)d_in[15];
    const float* eb2     = (const float*)d_in[16];
    const float* rootl   = (const float*)d_in[17];
    const float* biasl   = (const float*)d_in[18];
    const float* gammal  = (const float*)d_in[19];
    const float* betal   = (const float*)d_in[20];
    const float* pp_w1   = (const float*)d_in[21];
    const float* pp_b1   = (const float*)d_in[22];
    const float* pp_w2   = (const float*)d_in[23];
    const float* pp_b2   = (const float*)d_in[24];

    float* ws = (float*)d_ws;
    size_t off = 0;
    float* h      = ws + off; off += (size_t)N_EDGES * KDIM;   // 6.4M
    float* msg    = ws + off; off += (size_t)N_EDGES * 64;     // 3.2M
    float* agg    = ws + off; off += (size_t)N_NODES * 64;
    float* xa     = ws + off; off += (size_t)N_NODES * 64;
    float* xb     = ws + off; off += (size_t)N_NODES * 64;
    float* xb2    = ws + off; off += (size_t)N_NODES * 64;
    float* stats  = ws + off; off += 256;
    float* pooled = ws + off; off += (size_t)NG * 64;
    int*   cnt    = (int*)(ws + off); off += N_NODES;
    int*   offs   = (int*)(ws + off); off += N_NODES;
    int*   cur    = (int*)(ws + off); off += N_NODES;
    int*   srcs   = (int*)(ws + off); off += N_EDGES;
    int*   dsts   = (int*)(ws + off); off += N_EDGES;
    int*   perm   = (int*)(ws + off); off += N_EDGES;
    off = (off + 3) & ~(size_t)3;                      // 16B-align Y
    unsigned short* Y = (unsigned short*)(ws + off);

    // pick k-chunking so bf16 Y fits in workspace (deterministic given ws_size)
    int kc = 1;
    while (kc < 128 && off * 4 + (size_t)N_NODES * 8192 * 2 / kc > ws_size) kc <<= 1;
    const int kchunk = KDIM / kc;

    hipMemsetAsync(pooled, 0, (size_t)NG * 64 * 4, stream);
    hipMemsetAsync(cnt, 0, N_NODES * 4, stream);
    hipMemsetAsync(cur, 0, N_NODES * 4, stream);

    const int e256 = (N_EDGES + 255) / 256;
    hist_kernel<<<e256, 256, 0, stream>>>(src, cnt);
    scan_kernel<<<1, 1024, 0, stream>>>(cnt, offs);
    scatter_kernel<<<e256, 256, 0, stream>>>(src, dst, offs, cur, srcs, dsts, perm);

    struct Layer {
        const float *w1, *b1, *w2, *b2, *root, *bias, *gamma, *beta, *xin;
        float* xout; int in, inshift, mode;
    };
    Layer L[4];
    L[0] = {e0w1, e0b1, e0w2, e0b2, root0, bias0, gamma0, beta0, x0, xa, IN0, 5, 0};
    for (int l = 0; l < 3; l++) {
        const float* xin  = (l == 0) ? xa : ((l == 1) ? xb : xa);
        float*       xout = (l == 0) ? xb : ((l == 1) ? xa : nullptr);
        L[l + 1] = {ew1 + (size_t)l * EDGE_IN * KDIM, eb1 + (size_t)l * KDIM,
                    ew2 + (size_t)l * KDIM * (HID * HID), eb2 + (size_t)l * (HID * HID),
                    rootl + (size_t)l * HID * HID, biasl + (size_t)l * HID,
                    gammal + (size_t)l * HID, betal + (size_t)l * HID,
                    xin, xout, HID, 6, (l == 2) ? 1 : 0};
    }

    const int hblocks  = (int)(((size_t)N_EDGES * KDIM + 255) / 256);
    const int nblocks4 = (N_NODES + 3) / 4;
    const int vblocks  = (N_NODES + 127) / 128;
    const int eblocks  = (N_EDGES + 15) / 16;
    const int ablocks  = (N_NODES * 64 + 255) / 256;

    for (int l = 0; l < 4; l++) {
        const Layer& P = L[l];
        const int rowlen = P.in * 64;
        h_kernel<<<hblocks, 256, 0, stream>>>(ea, P.w1, P.b1, h);
        xb2_kernel<<<nblocks4, 256, 0, stream>>>(P.xin, P.b2, xb2, P.in, P.inshift);
        hipMemsetAsync(agg, 0, (size_t)N_NODES * 64 * 4, stream);
        hipMemsetAsync(stats, 0, 128 * 4, stream);
        for (int c = 0; c < kc; c++) {
            ygemm<<<dim3(vblocks, kchunk), 256, 0, stream>>>(
                P.xin, P.w2, Y, P.in, P.inshift, rowlen, c * kchunk, kchunk);
            msg_kernel<<<eblocks, 1024, 0, stream>>>(
                h, Y, srcs, dsts, perm, msg, xb2, agg, c * kchunk, kchunk,
                (c == 0) ? 1 : 0, (c == kc - 1) ? 1 : 0);
        }
        pre_stats<<<512, 256, 0, stream>>>(agg, P.xin, P.root, P.bias, agg, stats,
                                           P.in, P.inshift);
        bn_apply<<<ablocks, 256, 0, stream>>>(agg, stats, P.gamma, P.beta, P.xout,
                                              batch, pooled, P.mode);
    }
    final_mlp<<<NG, 64, 0, stream>>>(pooled, u, pp_w1, pp_b1, pp_w2, pp_b2,
                                     (float*)d_out);
}

// Round 4
// 924.979 us; speedup vs baseline: 2.6540x; 1.4709x over previous
//
#include <hip/hip_runtime.h>

#define N_NODES 10000
#define N_EDGES 50000
#define IN0     32
#define EDGE_IN 16
#define GIN     8
#define HID     64
#define NG      64
#define KDIM    128
#define EPS     1e-5f

typedef _Float16 f16;
typedef _Float16 v8h __attribute__((ext_vector_type(8)));
typedef float    v4f __attribute__((ext_vector_type(4)));

// ---------------------------------------------------------------------------
// ht[j][e] = f16(relu(ea[e]@w1[:,j] + b1[j]))  -- transposed for the fused GEMM
__global__ __launch_bounds__(256) void ht_kernel(const float* __restrict__ ea,
                                                 const float* __restrict__ w1,
                                                 const float* __restrict__ b1,
                                                 f16* __restrict__ ht) {
    __shared__ float eas[256][17];
    const int e0 = blockIdx.x * 256, t = threadIdx.x;
    for (int idx = t; idx < 256 * 16; idx += 256) {
        int r = idx >> 4, i = idx & 15;
        eas[r][i] = (e0 + r < N_EDGES) ? ea[(size_t)(e0 + r) * EDGE_IN + i] : 0.f;
    }
    __syncthreads();
    const int e = e0 + t;
#pragma unroll 1
    for (int j = 0; j < KDIM; j++) {
        float acc = b1[j];
#pragma unroll
        for (int i = 0; i < EDGE_IN; i++) acc += eas[t][i] * w1[i * KDIM + j];
        if (e < N_EDGES) ht[(size_t)j * N_EDGES + e] = (f16)fmaxf(acc, 0.f);
    }
}

// ---------------------------------------------------------------------------
// xf[idx] = f16(x[idx])
__global__ __launch_bounds__(256) void xconv(const float* __restrict__ x,
                                             f16* __restrict__ xf, int n) {
    int idx = blockIdx.x * 256 + threadIdx.x;
    if (idx < n) xf[idx] = (f16)x[idx];
}

// ---------------------------------------------------------------------------
// Bg[chunk][o][cc] = f16 of B[C=chunk*64+cc, o] where B[k*in+i, o]=w2[k][i*64+o],
// B[in*128+i, o]=b2[i*64+o], else 0.  (chunk = 64 K-rows of the flattened GEMM)
__global__ __launch_bounds__(256) void bconv(const float* __restrict__ w2,
                                             const float* __restrict__ b2,
                                             f16* __restrict__ Bg,
                                             int in, int inshift) {
    const int chunk = blockIdx.x;
    const int inK = in << 7;
    const size_t base = (size_t)chunk * 4096;
    for (int l = threadIdx.x; l < 4096; l += 256) {
        int o = l >> 6, cc = l & 63;
        int C = (chunk << 6) + cc;
        float v = 0.f;
        if (C < inK) {
            int k = C >> inshift, i = C & (in - 1);
            v = w2[(size_t)k * (in << 6) + (i << 6) + o];
        } else if (C < inK + in) {
            v = b2[((C - inK) << 6) + o];
        }
        Bg[base + l] = (f16)v;
    }
}

// ---------------------------------------------------------------------------
// Fused NNConv message+scatter:  agg[dst[e],o] += sum_C (h[e,k]*x[src,i]) * B[C,o]
// M=256 edges/block (4 waves x 64), N=64, K streamed in 64-chunks via LDS dbuf.
// A-fragments are rank-1 (h scalar x x-register), built in registers.
__global__ __launch_bounds__(256) void fused_msg(const f16* __restrict__ ht,
                                                 const f16* __restrict__ xf,
                                                 const f16* __restrict__ Bg,
                                                 const int* __restrict__ src,
                                                 const int* __restrict__ dst,
                                                 float* __restrict__ agg,
                                                 int in, int inshift, int nch) {
    __shared__ f16 Bs[2][64 * 72];   // rows padded 64->72 f16 to break bank stride
    __shared__ int dst_l[256];
    const int t = threadIdx.x;
    const int w = t >> 6, lane = t & 63;
    const int m = lane & 15, q = lane >> 4;
    const int e0 = blockIdx.x * 256;
    const int inK = in << 7;

    dst_l[t] = (e0 + t < N_EDGES) ? dst[e0 + t] : -1;

    // per-lane x fragments: x[v_s][p*32 + q*8 .. +7], fixed for whole K loop
    v8h xr[4][2];
    int eidx[4];
#pragma unroll
    for (int s = 0; s < 4; s++) {
        int e = e0 + w * 64 + s * 16 + m;
        eidx[s] = e < N_EDGES ? e : N_EDGES - 1;
        const f16* xrow = xf + (size_t)src[eidx[s]] * in;
        xr[s][0] = *(const v8h*)(xrow + q * 8);
        if (in == 64) xr[s][1] = *(const v8h*)(xrow + 32 + q * 8);
        else          xr[s][1] = xr[s][0];
    }

    // B staging geometry: thread copies 16 f16 (32B): row so, segment sseg
    const int so = t >> 2, sseg = t & 3;
    const size_t goff = (size_t)so * 64 + sseg * 16;
    const int    loff = so * 72 + sseg * 16;
    {
        const uint4* gp = (const uint4*)(Bg + goff);
        *((uint4*)(&Bs[0][loff]))     = gp[0];
        *((uint4*)(&Bs[0][loff + 8])) = gp[1];
    }
    __syncthreads();

    v4f acc[4][4] = {};
    int buf = 0;
    for (int c = 0; c < nch; c++) {
        uint4 r0, r1;
        const bool pf = (c + 1 < nch);
        if (pf) {
            const uint4* gp = (const uint4*)(Bg + (size_t)(c + 1) * 4096 + goff);
            r0 = gp[0]; r1 = gp[1];
        }
        const f16* bb = Bs[buf];
#pragma unroll
        for (int p = 0; p < 2; p++) {
            const int c0 = (c << 6) + (p << 5);
            if (c0 < inK + in) {
                const int xs = p & (in >> 6);   // 64->p, 32->0
                f16 hv[4];
                if (c0 < inK) {
                    const int k = c0 >> inshift;
                    const f16* hp = ht + (size_t)k * N_EDGES;
#pragma unroll
                    for (int s = 0; s < 4; s++) hv[s] = hp[eidx[s]];
                } else {
#pragma unroll
                    for (int s = 0; s < 4; s++) hv[s] = (f16)1.0f;
                }
                v8h bf[4];
#pragma unroll
                for (int tt = 0; tt < 4; tt++)
                    bf[tt] = *(const v8h*)(bb + (tt * 16 + m) * 72 + p * 32 + q * 8);
#pragma unroll
                for (int s = 0; s < 4; s++) {
                    v8h af;
#pragma unroll
                    for (int j = 0; j < 8; j++) af[j] = xr[s][xs][j] * hv[s];
#pragma unroll
                    for (int tt = 0; tt < 4; tt++)
                        acc[s][tt] = __builtin_amdgcn_mfma_f32_16x16x32_f16(
                            af, bf[tt], acc[s][tt], 0, 0, 0);
                }
            }
        }
        if (pf) {
            *((uint4*)(&Bs[buf ^ 1][loff]))     = r0;
            *((uint4*)(&Bs[buf ^ 1][loff + 8])) = r1;
        }
        __syncthreads();
        buf ^= 1;
    }

    // epilogue: C/D layout col=lane&15, row=quad*4+reg
#pragma unroll
    for (int s = 0; s < 4; s++) {
        const int el = w * 64 + s * 16 + q * 4;
#pragma unroll
        for (int r = 0; r < 4; r++) {
            const int d = dst_l[el + r];
            if (d >= 0) {
#pragma unroll
                for (int tt = 0; tt < 4; tt++)
                    atomicAdd(&agg[(size_t)d * 64 + tt * 16 + m], acc[s][tt][r]);
            }
        }
    }
}

// ---------------------------------------------------------------------------
// pre[n,o] = agg[n,o] + sum_i x[n,i]*root[i,o] + bias[o]; accumulate BN stats.
__global__ __launch_bounds__(256) void pre_stats(const float* __restrict__ agg,
                                                 const float* __restrict__ x,
                                                 const float* __restrict__ root,
                                                 const float* __restrict__ bias,
                                                 float* __restrict__ pre,
                                                 float* __restrict__ stats,
                                                 int in, int inshift) {
    __shared__ float xs[4][64];
    __shared__ float lsum[64], lsq[64];
    const int o = threadIdx.x & 63, nl = threadIdx.x >> 6;
    if (threadIdx.x < 64) { lsum[threadIdx.x] = 0.f; lsq[threadIdx.x] = 0.f; }
    const float bo = bias[o];
    for (int n0 = blockIdx.x * 4; n0 < N_NODES; n0 += gridDim.x * 4) {
        __syncthreads();
        for (int idx = threadIdx.x; idx < (4 << inshift); idx += 256) {
            int r = idx >> inshift, i = idx & (in - 1);
            if (n0 + r < N_NODES) xs[r][i] = x[(size_t)(n0 + r) * in + i];
        }
        __syncthreads();
        int n = n0 + nl;
        if (n < N_NODES) {
            float acc = agg[(size_t)n * 64 + o] + bo;
#pragma unroll 8
            for (int i = 0; i < in; i++) acc += xs[nl][i] * root[i * 64 + o];
            pre[(size_t)n * 64 + o] = acc;
            atomicAdd(&lsum[o], acc);
            atomicAdd(&lsq[o], acc * acc);
        }
    }
    __syncthreads();
    if (threadIdx.x < 64) {
        atomicAdd(&stats[threadIdx.x], lsum[threadIdx.x]);
        atomicAdd(&stats[64 + threadIdx.x], lsq[threadIdx.x]);
    }
}

// ---------------------------------------------------------------------------
// BN (batch stats, biased var) + ReLU. mode 0: store xn. mode 1: segment-max pool.
__global__ __launch_bounds__(256) void bn_apply(const float* __restrict__ pre,
                                                const float* __restrict__ stats,
                                                const float* __restrict__ gamma,
                                                const float* __restrict__ beta,
                                                float* __restrict__ xn,
                                                const int* __restrict__ batch,
                                                float* __restrict__ pooled,
                                                int mode) {
    int idx = blockIdx.x * 256 + threadIdx.x;
    if (idx >= N_NODES * 64) return;
    const int o = idx & 63, n = idx >> 6;
    const float inv = 1.f / (float)N_NODES;
    float mu = stats[o] * inv;
    float var = stats[64 + o] * inv - mu * mu;
    float sc = gamma[o] * rsqrtf(var + EPS);
    float sh = beta[o] - mu * sc;
    float v = fmaxf(pre[idx] * sc + sh, 0.f);
    if (mode == 0) xn[idx] = v;
    else atomicMax((int*)&pooled[(size_t)batch[n] * 64 + o], __float_as_int(v));
}

// ---------------------------------------------------------------------------
// out[g] = pp_b2 + relu(cat(pooled[g],u[g]) @ pp_w1 + pp_b1) @ pp_w2
__global__ __launch_bounds__(64) void final_mlp(const float* __restrict__ pooled,
                                                const float* __restrict__ u,
                                                const float* __restrict__ w1,
                                                const float* __restrict__ b1,
                                                const float* __restrict__ w2,
                                                const float* __restrict__ b2,
                                                float* __restrict__ out) {
    const int g = blockIdx.x, t = threadIdx.x;
    float acc = b1[t];
#pragma unroll 8
    for (int i = 0; i < 64; i++) acc += pooled[g * 64 + i] * w1[i * 64 + t];
#pragma unroll
    for (int j = 0; j < GIN; j++) acc += u[g * GIN + j] * w1[(64 + j) * 64 + t];
    float hv = fmaxf(acc, 0.f) * w2[t];
#pragma unroll
    for (int off = 32; off > 0; off >>= 1) hv += __shfl_down(hv, off, 64);
    if (t == 0) out[g] = hv + b2[0];
}

// ---------------------------------------------------------------------------
extern "C" void kernel_launch(void* const* d_in, const int* in_sizes, int n_in,
                              void* d_out, int out_size, void* d_ws, size_t ws_size,
                              hipStream_t stream) {
    const float* x0      = (const float*)d_in[0];
    const int*   ei      = (const int*)d_in[1];
    const int*   src     = ei;
    const int*   dst     = ei + N_EDGES;
    const float* ea      = (const float*)d_in[2];
    const int*   batch   = (const int*)d_in[3];
    const float* u       = (const float*)d_in[4];
    const float* e0w1    = (const float*)d_in[5];
    const float* e0b1    = (const float*)d_in[6];
    const float* e0w2    = (const float*)d_in[7];
    const float* e0b2    = (const float*)d_in[8];
    const float* root0   = (const float*)d_in[9];
    const float* bias0   = (const float*)d_in[10];
    const float* gamma0  = (const float*)d_in[11];
    const float* beta0   = (const float*)d_in[12];
    const float* ew1     = (const float*)d_in[13];
    const float* eb1     = (const float*)d_in[14];
    const float* ew2     = (const float*)d_in[15];
    const float* eb2     = (const float*)d_in[16];
    const float* rootl   = (const float*)d_in[17];
    const float* biasl   = (const float*)d_in[18];
    const float* gammal  = (const float*)d_in[19];
    const float* betal   = (const float*)d_in[20];
    const float* pp_w1   = (const float*)d_in[21];
    const float* pp_b1   = (const float*)d_in[22];
    const float* pp_w2   = (const float*)d_in[23];
    const float* pp_b2   = (const float*)d_in[24];

    float* ws = (float*)d_ws;
    size_t off = 0;
    f16*   ht     = (f16*)(ws + off); off += (size_t)N_EDGES * KDIM / 2;  // 3.2M fl
    f16*   xf     = (f16*)(ws + off); off += (size_t)N_NODES * 64 / 2;
    f16*   Bg     = (f16*)(ws + off); off += (size_t)129 * 4096 / 2;
    float* agg    = ws + off; off += (size_t)N_NODES * 64;
    float* xa     = ws + off; off += (size_t)N_NODES * 64;
    float* xb     = ws + off; off += (size_t)N_NODES * 64;
    float* stats  = ws + off; off += 256;
    float* pooled = ws + off; off += (size_t)NG * 64;

    hipMemsetAsync(pooled, 0, (size_t)NG * 64 * 4, stream);

    struct Layer {
        const float *w1, *b1, *w2, *b2, *root, *bias, *gamma, *beta, *xin;
        float* xout; int in, inshift, mode;
    };
    Layer L[4];
    L[0] = {e0w1, e0b1, e0w2, e0b2, root0, bias0, gamma0, beta0, x0, xa, IN0, 5, 0};
    for (int l = 0; l < 3; l++) {
        const float* xin  = (l == 0) ? xa : ((l == 1) ? xb : xa);
        float*       xout = (l == 0) ? xb : ((l == 1) ? xa : nullptr);
        L[l + 1] = {ew1 + (size_t)l * EDGE_IN * KDIM, eb1 + (size_t)l * KDIM,
                    ew2 + (size_t)l * KDIM * (HID * HID), eb2 + (size_t)l * (HID * HID),
                    rootl + (size_t)l * HID * HID, biasl + (size_t)l * HID,
                    gammal + (size_t)l * HID, betal + (size_t)l * HID,
                    xin, xout, HID, 6, (l == 2) ? 1 : 0};
    }

    const int eblocks = (N_EDGES + 255) / 256;               // 196
    const int ablocks = (N_NODES * 64 + 255) / 256;

    for (int l = 0; l < 4; l++) {
        const Layer& P = L[l];
        // nch: ceil((in*128 + in) / 64)
        const int nch = (P.in * 129 + 63) / 64;              // 258? no: in*129/64 -> 129 / 65
        ht_kernel<<<eblocks, 256, 0, stream>>>(ea, P.w1, P.b1, ht);
        xconv<<<(N_NODES * P.in + 255) / 256, 256, 0, stream>>>(P.xin, xf, N_NODES * P.in);
        bconv<<<nch, 256, 0, stream>>>(P.w2, P.b2, Bg, P.in, P.inshift);
        hipMemsetAsync(agg, 0, (size_t)N_NODES * 64 * 4, stream);
        hipMemsetAsync(stats, 0, 128 * 4, stream);
        fused_msg<<<eblocks, 256, 0, stream>>>(ht, xf, Bg, src, dst, agg,
                                               P.in, P.inshift, nch);
        pre_stats<<<512, 256, 0, stream>>>(agg, P.xin, P.root, P.bias, agg, stats,
                                           P.in, P.inshift);
        bn_apply<<<ablocks, 256, 0, stream>>>(agg, stats, P.gamma, P.beta, P.xout,
                                              batch, pooled, P.mode);
    }
    final_mlp<<<NG, 64, 0, stream>>>(pooled, u, pp_w1, pp_b1, pp_w2, pp_b2,
                                     (float*)d_out);
}